// Round 5
// baseline (512.606 us; speedup 1.0000x reference)
//
#include <hip/hip_runtime.h>

// Problem constants (from reference): B=16, S=512, T=16, P=4, G=S/P=128
#define SDIM 512
#define GDIM 128
#define TDIM 16

// Plain vector type: __builtin_nontemporal_load/store requires scalar or
// ext_vector_type pointers (HIP_vector_type float4 is rejected).
typedef float floatx4 __attribute__((ext_vector_type(4)));

// K1: per-patch CAM channel 0 + min/max normalization over t.
// Lane = (patch, t-quad): 4 lanes per patch, each owns 4 channels as a float4.
// Cache policy: input (268 MB) and weights (100 MB) are each read ONCE per launch
// -> nontemporal, so L2/L3 retention is reserved for `top` (16 MB, re-read 8x by K2).
// The 4x weight redundancy across quad lanes is same-instruction coalescing (L1/
// in-flight merge), not cache retention -> nt costs nothing there.
__global__ __launch_bounds__(256) void cam_patch_kernel(const float* __restrict__ inp,
                                                        const float* __restrict__ w3,
                                                        float* __restrict__ top) {
    const int t4 = threadIdx.x & 3;        // t-quad: channels t4*4 .. t4*4+3
    const int pp = threadIdx.x >> 2;       // patch within block, 0..63
    const int n  = blockIdx.x * 64 + pp;   // global patch id
    const int b  = n >> 14;                // / (128*128)
    const int gi = (n >> 7) & 127;
    const int gj = n & 127;

    const float* __restrict__ wp = w3 + (size_t)n * 96;   // 16x6 block, col 0 used

    floatx4 acc = (floatx4)(0.f);
#pragma unroll
    for (int r = 0; r < 4; ++r) {
        const floatx4* rowp = (const floatx4*)(inp
            + ((size_t)((b * SDIM + gi * 4 + r) * SDIM + gj * 4) * TDIM) + t4 * 4);
#pragma unroll
        for (int c = 0; c < 4; ++c) {
            const float wk = __builtin_nontemporal_load(wp + (r * 4 + c) * 6);
            const floatx4 x = __builtin_nontemporal_load(rowp + c * (TDIM / 4));
            acc += x * wk;
        }
    }

    // min/max over 16 channels: in-lane over the quad, then across the 4 patch lanes
    float mn = fminf(fminf(acc.x, acc.y), fminf(acc.z, acc.w));
    float mx = fmaxf(fmaxf(acc.x, acc.y), fmaxf(acc.z, acc.w));
    mn = fminf(mn, __shfl_xor(mn, 1, 4));
    mx = fmaxf(mx, __shfl_xor(mx, 1, 4));
    mn = fminf(mn, __shfl_xor(mn, 2, 4));
    mx = fmaxf(mx, __shfl_xor(mx, 2, 4));

    const float d = mx - mn;
    floatx4 o = (acc - mn) / d;

    // top layout (b, gi, gj, t): consecutive patches -> contiguous 1 KB per wave store.
    // top IS re-read by K2 -> regular (cached) store, stays L3-resident.
    *(floatx4*)(top + ((size_t)((b * GDIM + gi) * GDIM + gj) * TDIM) + t4 * 4) = o;
}

// K2: bilinear upsample (G,G)->(S,S), align_corners=True. One block per output row (b,o).
// Phase 1: blend the two source rows with the (per-block constant) wi ONCE into an
//          8 KB LDS row -> i-lerp hoisted out of the inner loop.
// Phase 2: per float4 output: 2x ds_read_b128 + 1 lerp + 1 nontemporal float4 store
//          (output is write-once, never re-read -> don't evict the 8x-reused top).
__global__ __launch_bounds__(256) void upsample_kernel(const float* __restrict__ top,
                                                       float* __restrict__ out) {
    __shared__ floatx4 lds[GDIM * TDIM / 4];   // blended row: 128*16 floats = 8 KB

    const int b = blockIdx.x >> 9;     // / 512
    const int o = blockIdx.x & 511;

    const float scale = 127.0f / 511.0f;
    const float ci = (float)o * scale;
    int i0 = (int)ci; if (i0 > GDIM - 2) i0 = GDIM - 2;
    const float wi = ci - (float)i0;

    // rows i0 and i0+1 are contiguous in (b,i,j,t) layout; cached reads (L3 hits)
    const floatx4* __restrict__ r0 = (const floatx4*)(top + (size_t)(b * GDIM + i0) * GDIM * TDIM);
    const floatx4* __restrict__ r1 = r0 + GDIM * TDIM / 4;
#pragma unroll
    for (int it = 0; it < 2; ++it) {
        const int idx = it * 256 + threadIdx.x;   // 0..511 float4s
        const floatx4 a = r0[idx];
        const floatx4 c = r1[idx];
        lds[idx] = a + wi * (c - a);
    }
    __syncthreads();

    floatx4* __restrict__ outp = (floatx4*)out + (size_t)(b * SDIM + o) * (SDIM * TDIM / 4);
#pragma unroll
    for (int it = 0; it < 8; ++it) {
        const int idx4 = it * 256 + threadIdx.x;  // 0..2047 = p*4 + q
        const int p = idx4 >> 2;
        const int q = idx4 & 3;
        const float cj = (float)p * scale;
        int j0 = (int)cj; if (j0 > GDIM - 2) j0 = GDIM - 2;
        const float wj = cj - (float)j0;

        const floatx4 a  = lds[j0 * 4 + q];
        const floatx4 bb = lds[j0 * 4 + 4 + q];
        const floatx4 v = a + wj * (bb - a);
        __builtin_nontemporal_store(v, outp + idx4);
    }
}

extern "C" void kernel_launch(void* const* d_in, const int* in_sizes, int n_in,
                              void* d_out, int out_size, void* d_ws, size_t ws_size,
                              hipStream_t stream) {
    const float* inp = (const float*)d_in[0];   // (16,512,512,16) fp32
    const float* w3  = (const float*)d_in[1];   // (262144,16,6) fp32
    float* out = (float*)d_out;                 // (16*512*512, 16) fp32
    float* top = (float*)d_ws;                  // (16,128,128,16) fp32 = 16 MB

    // K1: 262144 patches / 64 per block = 4096 blocks
    cam_patch_kernel<<<4096, 256, 0, stream>>>(inp, w3, top);
    // K2: one block per (b, o) output row = 16*512 = 8192 blocks
    upsample_kernel<<<8192, 256, 0, stream>>>(top, out);
}

// Round 6
// 497.229 us; speedup vs baseline: 1.0309x; 1.0309x over previous
//
#include <hip/hip_runtime.h>

// Problem constants (from reference): B=16, S=512, T=16, P=4, G=S/P=128
#define SDIM 512
#define GDIM 128
#define TDIM 16

// Plain vector type: __builtin_nontemporal_load/store requires scalar or
// ext_vector_type pointers (HIP_vector_type float4 is rejected).
typedef float floatx4 __attribute__((ext_vector_type(4)));

// K1: per-patch CAM channel 0 + min/max normalization over t.
// Lane = (patch, t-quad): 4 lanes per patch, each owns 4 channels as a float4.
// Cache policy (A/B-verified r4 vs r5):
//  - input (268 MB, read-once)  -> nontemporal  (keep L2/L3 for reused data)
//  - weights (100 MB)           -> CACHED: the col-0 gather issues 16 scalar
//    loads over 6 lines per patch; loads 2..16 hit L1 only if lines allocate.
//    nt here cost +13 us (r5).
//  - top (16 MB, re-read by K2) -> cached store.
__global__ __launch_bounds__(256) void cam_patch_kernel(const float* __restrict__ inp,
                                                        const float* __restrict__ w3,
                                                        float* __restrict__ top) {
    const int t4 = threadIdx.x & 3;        // t-quad: channels t4*4 .. t4*4+3
    const int pp = threadIdx.x >> 2;       // patch within block, 0..63
    const int n  = blockIdx.x * 64 + pp;   // global patch id
    const int b  = n >> 14;                // / (128*128)
    const int gi = (n >> 7) & 127;
    const int gj = n & 127;

    const float* __restrict__ wp = w3 + (size_t)n * 96;   // 16x6 block, col 0 used

    floatx4 acc = (floatx4)(0.f);
#pragma unroll
    for (int r = 0; r < 4; ++r) {
        const floatx4* rowp = (const floatx4*)(inp
            + ((size_t)((b * SDIM + gi * 4 + r) * SDIM + gj * 4) * TDIM) + t4 * 4);
#pragma unroll
        for (int c = 0; c < 4; ++c) {
            const float wk = wp[(r * 4 + c) * 6];
            const floatx4 x = __builtin_nontemporal_load(rowp + c * (TDIM / 4));
            acc += x * wk;
        }
    }

    // min/max over 16 channels: in-lane over the quad, then across the 4 patch lanes
    float mn = fminf(fminf(acc.x, acc.y), fminf(acc.z, acc.w));
    float mx = fmaxf(fmaxf(acc.x, acc.y), fmaxf(acc.z, acc.w));
    mn = fminf(mn, __shfl_xor(mn, 1, 4));
    mx = fmaxf(mx, __shfl_xor(mx, 1, 4));
    mn = fminf(mn, __shfl_xor(mn, 2, 4));
    mx = fmaxf(mx, __shfl_xor(mx, 2, 4));

    const float d = mx - mn;
    floatx4 o = (acc - mn) / d;

    // top layout (b, gi, gj, t): consecutive patches -> contiguous 1 KB per wave store.
    // top IS re-read by K2 -> regular (cached) store, stays L3-resident.
    *(floatx4*)(top + ((size_t)((b * GDIM + gi) * GDIM + gj) * TDIM) + t4 * 4) = o;
}

// K2: bilinear upsample (G,G)->(S,S), align_corners=True. One block per output row (b,o).
// Phase 1: blend the two source rows with the (per-block constant) wi ONCE into an
//          8 KB LDS row -> i-lerp hoisted out of the inner loop.
// Phase 2: per float4 output: 2x ds_read_b128 + 1 lerp + 1 nontemporal float4 store
//          (output is write-once, never re-read -> don't evict the 8x-reused top).
__global__ __launch_bounds__(256) void upsample_kernel(const float* __restrict__ top,
                                                       float* __restrict__ out) {
    __shared__ floatx4 lds[GDIM * TDIM / 4];   // blended row: 128*16 floats = 8 KB

    const int b = blockIdx.x >> 9;     // / 512
    const int o = blockIdx.x & 511;

    const float scale = 127.0f / 511.0f;
    const float ci = (float)o * scale;
    int i0 = (int)ci; if (i0 > GDIM - 2) i0 = GDIM - 2;
    const float wi = ci - (float)i0;

    // rows i0 and i0+1 are contiguous in (b,i,j,t) layout; cached reads (L3 hits)
    const floatx4* __restrict__ r0 = (const floatx4*)(top + (size_t)(b * GDIM + i0) * GDIM * TDIM);
    const floatx4* __restrict__ r1 = r0 + GDIM * TDIM / 4;
#pragma unroll
    for (int it = 0; it < 2; ++it) {
        const int idx = it * 256 + threadIdx.x;   // 0..511 float4s
        const floatx4 a = r0[idx];
        const floatx4 c = r1[idx];
        lds[idx] = a + wi * (c - a);
    }
    __syncthreads();

    floatx4* __restrict__ outp = (floatx4*)out + (size_t)(b * SDIM + o) * (SDIM * TDIM / 4);
#pragma unroll
    for (int it = 0; it < 8; ++it) {
        const int idx4 = it * 256 + threadIdx.x;  // 0..2047 = p*4 + q
        const int p = idx4 >> 2;
        const int q = idx4 & 3;
        const float cj = (float)p * scale;
        int j0 = (int)cj; if (j0 > GDIM - 2) j0 = GDIM - 2;
        const float wj = cj - (float)j0;

        const floatx4 a  = lds[j0 * 4 + q];
        const floatx4 bb = lds[j0 * 4 + 4 + q];
        const floatx4 v = a + wj * (bb - a);
        __builtin_nontemporal_store(v, outp + idx4);
    }
}

extern "C" void kernel_launch(void* const* d_in, const int* in_sizes, int n_in,
                              void* d_out, int out_size, void* d_ws, size_t ws_size,
                              hipStream_t stream) {
    const float* inp = (const float*)d_in[0];   // (16,512,512,16) fp32
    const float* w3  = (const float*)d_in[1];   // (262144,16,6) fp32
    float* out = (float*)d_out;                 // (16*512*512, 16) fp32
    float* top = (float*)d_ws;                  // (16,128,128,16) fp32 = 16 MB

    // K1: 262144 patches / 64 per block = 4096 blocks
    cam_patch_kernel<<<4096, 256, 0, stream>>>(inp, w3, top);
    // K2: one block per (b, o) output row = 16*512 = 8192 blocks
    upsample_kernel<<<8192, 256, 0, stream>>>(top, out);
}